// Round 1
// 1454.002 us; speedup vs baseline: 1.1068x; 1.1068x over previous
//
#include <hip/hip_runtime.h>
#include <math.h>

#define FIN  1433
#define HID  67
#define HIDP 68
#define NC   7
#define NCP  8

#define BK     32
#define KTILES 45            // ceil(1433/32)
#define KPAD   (KTILES*BK)   // 1440
#define COLP   80            // 5 tiles of 16 (67 real cols, rest zero)

typedef __attribute__((ext_vector_type(8))) short short8;
typedef __attribute__((ext_vector_type(4))) float floatx4;

static __device__ inline unsigned short f2bf(float f) {
    unsigned int u = __float_as_uint(f);
    unsigned int r = (u + 0x7fffu + ((u >> 16) & 1u)) >> 16;   // RNE
    return (unsigned short)r;
}

// ---------------- CSR build ----------------

__global__ void k_zero(int* __restrict__ cnt, int N) {
    int i = blockIdx.x * 256 + threadIdx.x;
    if (i < N) cnt[i] = 0;
}

__global__ void k_count(const int* __restrict__ dst, int* __restrict__ cnt, int E) {
    int e = blockIdx.x * 256 + threadIdx.x;
    if (e < E) atomicAdd(&cnt[dst[e]], 1);
}

__global__ void k_bsum(const int* __restrict__ cnt, int* __restrict__ bsum, int N) {
    __shared__ int s[256];
    int t = threadIdx.x;
    int i = blockIdx.x * 256 + t;
    s[t] = (i < N) ? cnt[i] : 0;
    __syncthreads();
    for (int o = 128; o > 0; o >>= 1) {
        if (t < o) s[t] += s[t + o];
        __syncthreads();
    }
    if (t == 0) bsum[blockIdx.x] = s[0];
}

// exclusive scan of block sums; nb <= 512
__global__ void k_scanb(int* __restrict__ bsum, int nb) {
    __shared__ int s[512];
    int t = threadIdx.x;
    int v = (t < nb) ? bsum[t] : 0;
    s[t] = v;
    __syncthreads();
    for (int o = 1; o < 512; o <<= 1) {
        int tmp = (t >= o) ? s[t - o] : 0;
        __syncthreads();
        s[t] += tmp;
        __syncthreads();
    }
    if (t < nb) bsum[t] = s[t] - v;  // exclusive
}

__global__ void k_scan3(const int* __restrict__ cnt, const int* __restrict__ bsum,
                        int* __restrict__ rowptr, int* __restrict__ cursor,
                        float* __restrict__ dinv, int N, int E) {
    __shared__ int s[256];
    int t = threadIdx.x;
    int i = blockIdx.x * 256 + t;
    int v = (i < N) ? cnt[i] : 0;
    s[t] = v;
    __syncthreads();
    for (int o = 1; o < 256; o <<= 1) {
        int tmp = (t >= o) ? s[t - o] : 0;
        __syncthreads();
        s[t] += tmp;
        __syncthreads();
    }
    if (i < N) {
        int start = bsum[blockIdx.x] + s[t] - v;  // exclusive global prefix
        rowptr[i] = start;
        cursor[i] = start;
        dinv[i]   = rsqrtf((float)(v + 1));       // +1 self loop
    }
    if (i == 0) rowptr[N] = E;
}

__global__ void k_fill(const int* __restrict__ ei, int* __restrict__ cursor,
                       int* __restrict__ csrs, int E) {
    int e = blockIdx.x * 256 + threadIdx.x;
    if (e < E) {
        int s = ei[e];          // source
        int d = ei[E + e];      // target
        int pos = atomicAdd(&cursor[d], 1);
        csrs[pos] = s;
    }
}

// ---------------- W1 -> bf16 [col][k] padded; plus xpad = padded copy of row N-1 ----

__global__ void k_wcvt(const float* __restrict__ W1, const float* __restrict__ x,
                       unsigned short* __restrict__ Wt, float* __restrict__ xpad, int N) {
    int idx = blockIdx.x * 256 + threadIdx.x;
    if (idx < KPAD) xpad[idx] = (idx < FIN) ? x[(long long)(N - 1) * FIN + idx] : 0.f;
    if (idx >= COLP * KPAD) return;
    int col = idx / KPAD;
    int k   = idx - col * KPAD;
    float v = (col < HID && k < FIN) ? W1[k * HID + col] : 0.f;
    Wt[idx] = f2bf(v);
}

// ---------------- GEMM1 (MFMA bf16, no LDS, no barriers) ----------------
// h1s[N,68] = dinv[r] * (x[N,1433] @ W1).  Block: 128 rows, 4 waves.
// Wave owns 32 rows (2 A-frags). A loads direct HBM->reg (rows are wave-exclusive,
// LDS staging was pure overhead). B-frags direct from L2-resident Wt.
// Hand-pipelined x2: next tile's A loads issue before current tile's MFMAs.

#define GEMM1_LOAD(Abuf, KT) do {                       \
        __builtin_memcpy(&Abuf[0], xp0 + (KT), 32);     \
        __builtin_memcpy(&Abuf[8], xp1 + (KT), 32);     \
    } while (0)

#define GEMM1_STEP(Abuf, KT) do {                                                   \
        short8 fa0, fa1;                                                            \
        _Pragma("unroll")                                                           \
        for (int u = 0; u < 8; u++) {                                               \
            fa0[u] = (short)f2bf(Abuf[u]);                                          \
            fa1[u] = (short)f2bf(Abuf[8 + u]);                                      \
        }                                                                           \
        _Pragma("unroll")                                                           \
        for (int j = 0; j < 5; j++) {                                               \
            short8 bf = *(const short8*)(wb + j * 16 * KPAD + (KT));                \
            acc0[j] = __builtin_amdgcn_mfma_f32_16x16x32_bf16(fa0, bf, acc0[j], 0, 0, 0); \
            acc1[j] = __builtin_amdgcn_mfma_f32_16x16x32_bf16(fa1, bf, acc1[j], 0, 0, 0); \
        }                                                                           \
    } while (0)

__global__ __launch_bounds__(256) void k_gemm1(const float* __restrict__ x,
                                               const unsigned short* __restrict__ Wt,
                                               const float* __restrict__ dinv,
                                               const float* __restrict__ xpad,
                                               float* __restrict__ h1s, int N) {
    int t    = threadIdx.x;
    int lane = t & 63;
    int w    = t >> 6;
    int lm   = lane & 15;
    int lq   = lane >> 4;
    int row0w = blockIdx.x * 128 + w * 32;

    int r0 = row0w + lm;
    int r1 = row0w + 16 + lm;
    // Row N-1 (and clamped tail rows) read from xpad: zero-padded to KPAD,
    // so k-overreads past FIN are safe everywhere (x rows < N-1 spill into the
    // next row, which is in-bounds and multiplied by zero-padded B anyway).
    const float* xp0 = (r0 >= N - 1) ? xpad : (x + (long long)r0 * FIN);
    const float* xp1 = (r1 >= N - 1) ? xpad : (x + (long long)r1 * FIN);
    xp0 += lq * 8;
    xp1 += lq * 8;
    const unsigned short* wb = Wt + lm * KPAD + lq * 8;

    floatx4 acc0[5], acc1[5];
#pragma unroll
    for (int j = 0; j < 5; j++) {
        acc0[j] = (floatx4){0.f, 0.f, 0.f, 0.f};
        acc1[j] = (floatx4){0.f, 0.f, 0.f, 0.f};
    }

    float A0[16], A1[16];
    GEMM1_LOAD(A0, 0);
    int kt = 0;
    for (; kt + 2 * BK < KPAD; kt += 2 * BK) {   // kt = 0..1344, computes tiles 0..1376
        GEMM1_LOAD(A1, kt + BK);
        GEMM1_STEP(A0, kt);
        GEMM1_LOAD(A0, kt + 2 * BK);
        GEMM1_STEP(A1, kt + BK);
    }
    GEMM1_STEP(A0, kt);                           // kt == 1408, tile 45

    // epilogue: C/D col=lane&15, row=lq*4+i ; pre-scale by dinv
#pragma unroll
    for (int i = 0; i < 4; i++) {
        int row = row0w + lq * 4 + i;
        if (row < N) {
            float dv = dinv[row];
            long long off = (long long)row * HIDP;
#pragma unroll
            for (int j = 0; j < 5; j++) {
                int col = j * 16 + lm;
                if (col < HIDP) h1s[off + col] = dv * acc0[j][i];
            }
        }
        int row2 = row0w + 16 + lq * 4 + i;
        if (row2 < N) {
            float dv = dinv[row2];
            long long off = (long long)row2 * HIDP;
#pragma unroll
            for (int j = 0; j < 5; j++) {
                int col = j * 16 + lm;
                if (col < HIDP) h1s[off + col] = dv * acc1[j][i];
            }
        }
    }
}

// ---------------- agg1: out1 = lrelu(b1 + dd*(h1s[d] + sum_e h1s[s])) ----------------
// h1s is pre-scaled by dinv -> no dinv gather in the loop. Unroll x4 for MLP.

__global__ __launch_bounds__(256) void k_agg1(const float* __restrict__ h1s,
                                              const int* __restrict__ rowptr,
                                              const int* __restrict__ csrs,
                                              const float* __restrict__ dinv,
                                              const float* __restrict__ bias1,
                                              float* __restrict__ out1, int N) {
    int lane = threadIdx.x & 63;
    int d = blockIdx.x * 4 + (threadIdx.x >> 6);   // wave per node
    if (d >= N) return;
    int start = rowptr[d];
    int end   = rowptr[d + 1];
    int tl = 64 + (lane & 3);   // tail col, broadcast across 16 lane-groups (same line)

    float m0 = 0.f, m1 = 0.f, m2 = 0.f, m3 = 0.f;
    float t0 = 0.f, t1 = 0.f, t2 = 0.f, t3 = 0.f;
    int e = start;
    for (; e + 4 <= end; e += 4) {
        int s0 = csrs[e], s1 = csrs[e + 1], s2 = csrs[e + 2], s3 = csrs[e + 3];
        const float* p0 = h1s + (long long)s0 * HIDP;
        const float* p1 = h1s + (long long)s1 * HIDP;
        const float* p2 = h1s + (long long)s2 * HIDP;
        const float* p3 = h1s + (long long)s3 * HIDP;
        m0 += p0[lane];  t0 += p0[tl];
        m1 += p1[lane];  t1 += p1[tl];
        m2 += p2[lane];  t2 += p2[tl];
        m3 += p3[lane];  t3 += p3[tl];
    }
    for (; e < end; e++) {
        const float* p = h1s + (long long)csrs[e] * HIDP;
        m0 += p[lane];
        t0 += p[tl];
    }
    float dd = dinv[d];
    const float* pd = h1s + (long long)d * HIDP;
    float sa = ((m0 + m1) + (m2 + m3)) + pd[lane];
    float sb = ((t0 + t1) + (t2 + t3)) + pd[tl];
    float vm = bias1[lane] + dd * sa;
    out1[(long long)d * HIDP + lane] = vm > 0.f ? vm : 0.01f * vm;
    if (lane < 4) {
        int j = 64 + lane;
        float bb = (j < HID) ? bias1[j] : 0.f;
        float vt = bb + dd * sb;                 // j=67: h1s col 67 == 0 -> stays 0
        out1[(long long)d * HIDP + j] = vt > 0.f ? vt : 0.01f * vt;
    }
}

// ---------------- GEMM2: h2s[N,8] = dinv * (out1[N,68] @ W2[67,7]) ----------------

__global__ __launch_bounds__(256) void k_gemm2(const float* __restrict__ out1,
                                               const float* __restrict__ W2,
                                               const float* __restrict__ dinv,
                                               float* __restrict__ h2s, int N) {
    __shared__ float w2s[HIDP][NCP];
    int t = threadIdx.x;
    for (int idx = t; idx < HIDP * NCP; idx += 256) {
        int k = idx >> 3, j = idx & 7;
        w2s[k][j] = (k < HID && j < NC) ? W2[k * NC + j] : 0.f;
    }
    __syncthreads();
    int i = blockIdx.x * 256 + t;
    if (i >= N) return;
    const float4* row = (const float4*)(out1 + (long long)i * HIDP);
    float acc[NC];
#pragma unroll
    for (int j = 0; j < NC; j++) acc[j] = 0.f;
#pragma unroll
    for (int kq = 0; kq < 17; kq++) {
        float4 v = row[kq];
        float av[4] = {v.x, v.y, v.z, v.w};
#pragma unroll
        for (int c = 0; c < 4; c++) {
            int k = kq * 4 + c;
            float a = av[c];
#pragma unroll
            for (int j = 0; j < NC; j++) acc[j] = fmaf(a, w2s[k][j], acc[j]);
        }
    }
    float dv = dinv[i];
    float* hp = h2s + (long long)i * NCP;
#pragma unroll
    for (int j = 0; j < NC; j++) hp[j] = dv * acc[j];
    hp[NC] = 0.f;   // pad col 7
}

// ---------------- agg2 + fused log_softmax ----------------
// Wave per node: lane = (edge_slot 0..7)*8 + (col 0..7). 8 edges/iter, csrs reads
// are one contiguous 32B line. h2s pre-scaled -> no dinv in loop. shfl reductions.

__global__ __launch_bounds__(256) void k_agg2(const float* __restrict__ h2s,
                                              const int* __restrict__ rowptr,
                                              const int* __restrict__ csrs,
                                              const float* __restrict__ dinv,
                                              const float* __restrict__ b2,
                                              float* __restrict__ out, int N) {
    int lane = threadIdx.x & 63;
    int d = blockIdx.x * 4 + (threadIdx.x >> 6);   // wave per node
    if (d >= N) return;
    int es = lane >> 3;     // edge slot
    int j  = lane & 7;      // class col
    int start = rowptr[d], end = rowptr[d + 1];
    float acc = 0.f;
    for (int e = start + es; e < end; e += 8) {
        int s = csrs[e];
        acc += h2s[(long long)s * NCP + j];
    }
#pragma unroll
    for (int o = 32; o >= 8; o >>= 1) acc += __shfl_xor(acc, o);   // sum over edge slots
    float dd = dinv[d];
    float self = h2s[(long long)d * NCP + j];
    float v = ((j < NC) ? b2[j] : 0.f) + dd * (self + acc);
    // log_softmax over 7 classes (mask pad col 7)
    float mv = (j == NC) ? -1e30f : v;
#pragma unroll
    for (int o = 4; o >= 1; o >>= 1) mv = fmaxf(mv, __shfl_xor(mv, o));
    float ex = (j == NC) ? 0.f : __expf(v - mv);
    float ss = ex;
#pragma unroll
    for (int o = 4; o >= 1; o >>= 1) ss += __shfl_xor(ss, o);
    if (lane < 8 && j < NC) {
        out[(long long)d * NC + j] = v - mv - __logf(ss);
    }
}

// ---------------- launch ----------------

extern "C" void kernel_launch(void* const* d_in, const int* in_sizes, int n_in,
                              void* d_out, int out_size, void* d_ws, size_t ws_size,
                              hipStream_t stream) {
    const float* x  = (const float*)d_in[0];
    const int*   ei = (const int*)d_in[1];
    const float* W1 = (const float*)d_in[2];
    const float* b1 = (const float*)d_in[3];
    const float* W2 = (const float*)d_in[4];
    const float* b2 = (const float*)d_in[5];
    float* out = (float*)d_out;

    int N = in_sizes[0] / FIN;   // 100000
    int E = in_sizes[1] / 2;     // 3200000

    size_t o = 0;
    auto alloc = [&](size_t words) { size_t r = o; o += words; o = (o + 63) & ~(size_t)63; return r; };
    size_t o_dinv   = alloc((size_t)N);
    size_t o_cnt    = alloc((size_t)N);
    size_t o_rowptr = alloc((size_t)N + 1);
    size_t o_cursor = alloc((size_t)N);
    size_t o_bsum   = alloc(1024);
    size_t o_csrs   = alloc((size_t)E);
    size_t o_wt     = alloc((size_t)COLP * KPAD / 2);   // bf16, u32 words
    size_t o_xpad   = alloc((size_t)KPAD);
    size_t o_h1s    = alloc((size_t)N * HIDP);
    size_t o_out1   = alloc((size_t)N * HIDP);
    size_t o_h2s    = alloc((size_t)N * NCP);

    float* wsf = (float*)d_ws;
    int*   wsi = (int*)d_ws;
    float* dinv   = wsf + o_dinv;
    int*   cnt    = wsi + o_cnt;
    int*   rowptr = wsi + o_rowptr;
    int*   cursor = wsi + o_cursor;
    int*   bsum   = wsi + o_bsum;
    int*   csrs   = wsi + o_csrs;
    unsigned short* Wt = (unsigned short*)(wsi + o_wt);
    float* xpad   = wsf + o_xpad;
    float* h1s    = wsf + o_h1s;
    float* o1     = wsf + o_out1;
    float* h2s    = wsf + o_h2s;

    int nb = (N + 255) / 256;        // 391
    int eb = (E + 255) / 256;        // 12500
    int gb = (N + 127) / 128;        // 782 blocks for gemm1 (128 rows each)

    k_zero <<<nb, 256, 0, stream>>>(cnt, N);
    k_count<<<eb, 256, 0, stream>>>(ei + E, cnt, E);
    k_bsum <<<nb, 256, 0, stream>>>(cnt, bsum, N);
    k_scanb<<<1, 512, 0, stream>>>(bsum, nb);
    k_scan3<<<nb, 256, 0, stream>>>(cnt, bsum, rowptr, cursor, dinv, N, E);
    k_fill <<<eb, 256, 0, stream>>>(ei, cursor, csrs, E);

    k_wcvt <<<(COLP * KPAD + 255) / 256, 256, 0, stream>>>(W1, x, Wt, xpad, N);
    k_gemm1<<<gb, 256, 0, stream>>>(x, Wt, dinv, xpad, h1s, N);
    k_agg1 <<<(N + 3) / 4, 256, 0, stream>>>(h1s, rowptr, csrs, dinv, b1, o1, N);
    k_gemm2<<<nb, 256, 0, stream>>>(o1, W2, dinv, h2s, N);
    k_agg2 <<<(N + 3) / 4, 256, 0, stream>>>(h2s, rowptr, csrs, dinv, b2, out, N);
}